// Round 1
// baseline (7989.215 us; speedup 1.0000x reference)
//
#include <hip/hip_runtime.h>

// ---------------- device helpers ----------------

__device__ __forceinline__ void atomAddF(float* p, float v) {
    unsafeAtomicAdd(p, v);   // global_atomic_add_f32 on gfx950
}

// ---------------- fused 2-layer embedding MLP ----------------
// Y = relu( relu(X@W0 + b0) @ W1 + b1 ),  X:[M,K0], W0:[K0,64], W1:[64,64]
template<int K0>
__global__ __launch_bounds__(256) void emb_kernel(
    const float* __restrict__ X,
    const float* __restrict__ W0, const float* __restrict__ B0,
    const float* __restrict__ W1, const float* __restrict__ B1,
    float* __restrict__ Y, int M)
{
    const int lane = threadIdx.x & 63;
    const int wv   = threadIdx.x >> 6;

    float w0[K0];
#pragma unroll
    for (int k = 0; k < K0; ++k) w0[k] = W0[k*64 + lane];
    float w1[64];
#pragma unroll
    for (int k = 0; k < 64; ++k) w1[k] = W1[k*64 + lane];
    const float b0 = B0[lane];
    const float b1 = B1[lane];

    __shared__ __align__(16) float xs[4][8*K0];
    __shared__ __align__(16) float hb[4][8][64];

    const int rowTile = (blockIdx.x*4 + wv)*8;
    for (int idx = lane; idx < 8*K0; idx += 64) {
        long gi = (long)rowTile*K0 + idx;
        xs[wv][idx] = (gi < (long)M*K0) ? X[gi] : 0.f;
    }
    __syncthreads();

#pragma unroll
    for (int r = 0; r < 8; ++r) {
        float acc = b0;
#pragma unroll
        for (int k = 0; k < K0; ++k) acc = fmaf(xs[wv][r*K0 + k], w0[k], acc);
        hb[wv][r][lane] = fmaxf(acc, 0.f);
    }
    __syncthreads();

#pragma unroll
    for (int r = 0; r < 8; ++r) {
        float acc = b1;
#pragma unroll
        for (int k4 = 0; k4 < 16; ++k4) {
            float4 h4 = *(const float4*)&hb[wv][r][k4*4];
            acc = fmaf(h4.x, w1[k4*4+0], acc);
            acc = fmaf(h4.y, w1[k4*4+1], acc);
            acc = fmaf(h4.z, w1[k4*4+2], acc);
            acc = fmaf(h4.w, w1[k4*4+3], acc);
        }
        int row = rowTile + r;
        if (row < M) Y[(size_t)row*64 + lane] = fmaxf(acc, 0.f);
    }
}

// ---------------- generic Y = act(X@W + bias) , K=64, N=64 ----------------
// BIAS: 0 = none, 1 = +b[n], 2 = +b[n]*rowscale[row]
template<bool RELU, int BIAS>
__global__ __launch_bounds__(256) void lin64_kernel(
    const float* __restrict__ X, const float* __restrict__ W,
    const float* __restrict__ bias, const float* __restrict__ rowscale,
    float* __restrict__ Y, int M)
{
    const int lane = threadIdx.x & 63;
    const int wv   = threadIdx.x >> 6;

    float w[64];
#pragma unroll
    for (int k = 0; k < 64; ++k) w[k] = W[k*64 + lane];
    const float bb = (BIAS >= 1) ? bias[lane] : 0.f;

    __shared__ __align__(16) float xs[4][8][64];
    const int rowTile = (blockIdx.x*4 + wv)*8;

#pragma unroll
    for (int r = 0; r < 8; ++r) {
        int row = rowTile + r;
        int grow = (row < M) ? row : (M - 1);
        xs[wv][r][lane] = X[(size_t)grow*64 + lane];
    }
    __syncthreads();

    float acc[8];
#pragma unroll
    for (int r = 0; r < 8; ++r) acc[r] = 0.f;

#pragma unroll
    for (int k4 = 0; k4 < 16; ++k4) {
#pragma unroll
        for (int r = 0; r < 8; ++r) {
            float4 x4 = *(const float4*)&xs[wv][r][k4*4];
            acc[r] = fmaf(x4.x, w[k4*4+0], acc[r]);
            acc[r] = fmaf(x4.y, w[k4*4+1], acc[r]);
            acc[r] = fmaf(x4.z, w[k4*4+2], acc[r]);
            acc[r] = fmaf(x4.w, w[k4*4+3], acc[r]);
        }
    }

#pragma unroll
    for (int r = 0; r < 8; ++r) {
        int row = rowTile + r;
        if (row >= M) continue;
        float v = acc[r];
        if (BIAS == 1) v += bb;
        if (BIAS == 2) v += bb * rowscale[row];
        if (RELU) v = fmaxf(v, 0.f);
        Y[(size_t)row*64 + lane] = v;
    }
}

// ---------------- Y = act( concat(X1,X2) @ W + b ) , K=128, N=64 ----------------
template<bool RELU>
__global__ __launch_bounds__(256) void lin128_kernel(
    const float* __restrict__ X1, const float* __restrict__ X2,
    const float* __restrict__ W /*[128][64]*/, const float* __restrict__ bias,
    float* __restrict__ Y, int M)
{
    const int lane = threadIdx.x & 63;
    const int wv   = threadIdx.x >> 6;

    __shared__ __align__(16) float xs[4][8][128];
    const int rowTile = (blockIdx.x*4 + wv)*8;

#pragma unroll
    for (int r = 0; r < 8; ++r) {
        int row = rowTile + r;
        int grow = (row < M) ? row : (M - 1);
        xs[wv][r][lane]      = X1[(size_t)grow*64 + lane];
        xs[wv][r][64 + lane] = X2[(size_t)grow*64 + lane];
    }
    __syncthreads();

    float acc[8];
#pragma unroll
    for (int r = 0; r < 8; ++r) acc[r] = 0.f;

    float w[64];
    // chunk 0 (k = 0..63)
#pragma unroll
    for (int k = 0; k < 64; ++k) w[k] = W[k*64 + lane];
#pragma unroll
    for (int k4 = 0; k4 < 16; ++k4) {
#pragma unroll
        for (int r = 0; r < 8; ++r) {
            float4 x4 = *(const float4*)&xs[wv][r][k4*4];
            acc[r] = fmaf(x4.x, w[k4*4+0], acc[r]);
            acc[r] = fmaf(x4.y, w[k4*4+1], acc[r]);
            acc[r] = fmaf(x4.z, w[k4*4+2], acc[r]);
            acc[r] = fmaf(x4.w, w[k4*4+3], acc[r]);
        }
    }
    // chunk 1 (k = 64..127)
#pragma unroll
    for (int k = 0; k < 64; ++k) w[k] = W[(64 + k)*64 + lane];
#pragma unroll
    for (int k4 = 0; k4 < 16; ++k4) {
#pragma unroll
        for (int r = 0; r < 8; ++r) {
            float4 x4 = *(const float4*)&xs[wv][r][64 + k4*4];
            acc[r] = fmaf(x4.x, w[k4*4+0], acc[r]);
            acc[r] = fmaf(x4.y, w[k4*4+1], acc[r]);
            acc[r] = fmaf(x4.z, w[k4*4+2], acc[r]);
            acc[r] = fmaf(x4.w, w[k4*4+3], acc[r]);
        }
    }

    const float bb = bias[lane];
#pragma unroll
    for (int r = 0; r < 8; ++r) {
        int row = rowTile + r;
        if (row >= M) continue;
        float v = acc[r] + bb;
        if (RELU) v = fmaxf(v, 0.f);
        Y[(size_t)row*64 + lane] = v;
    }
}

// ---------------- edge scatter: aggpre[dst] += relu(Rl[dst]+Ls[src]+ef*ew) ----------------
__global__ __launch_bounds__(256) void edge_kernel(
    const int* __restrict__ dstIdx, const int* __restrict__ srcIdx,
    const float* __restrict__ ef,
    const float* __restrict__ Rl,  // [Ndst,64]  (right-linear, indexed by dst)
    const float* __restrict__ Ls,  // [Nsrc,64]  (left-linear, indexed by src)
    const float* __restrict__ ew,  // [64]
    float* __restrict__ aggpre,    // [Ndst,64]  zero-initialized
    float* __restrict__ deg,       // [Ndst]     zero-initialized
    int E)
{
    int t = blockIdx.x*256 + threadIdx.x;
    int e = t >> 4;
    int q = t & 15;
    if (e >= E) return;

    const int d = dstIdx[e];
    const int s = srcIdx[e];
    const float f = ef[e];

    float4 a = *(const float4*)&Rl[(size_t)d*64 + q*4];
    float4 b = *(const float4*)&Ls[(size_t)s*64 + q*4];
    float4 w = *(const float4*)&ew[q*4];

    float p0 = fmaxf(a.x + b.x + f*w.x, 0.f);
    float p1 = fmaxf(a.y + b.y + f*w.y, 0.f);
    float p2 = fmaxf(a.z + b.z + f*w.z, 0.f);
    float p3 = fmaxf(a.w + b.w + f*w.w, 0.f);

    float* o = &aggpre[(size_t)d*64 + q*4];
    atomAddF(o + 0, p0);
    atomAddF(o + 1, p1);
    atomAddF(o + 2, p2);
    atomAddF(o + 3, p3);
    if (q == 0) atomAddF(&deg[d], 1.0f);
}

// ---------------- fused heads: value & policy ----------------
__global__ __launch_bounds__(256) void head_kernel(
    const float* __restrict__ Xv,
    const float* __restrict__ PW0, const float* __restrict__ PB0, const float* __restrict__ PW1,
    const float* __restrict__ VW0, const float* __restrict__ VB0, const float* __restrict__ VW1,
    const float* __restrict__ VB1,
    float* __restrict__ out, int M)
{
    const int lane = threadIdx.x & 63;
    const int wv   = threadIdx.x >> 6;

    float wp[64], wq[64];
#pragma unroll
    for (int k = 0; k < 64; ++k) { wp[k] = PW0[k*64 + lane]; wq[k] = VW0[k*64 + lane]; }
    const float bp = PB0[lane];
    const float bv = VB0[lane];
    const float pw1l = PW1[lane];
    const float vw1l = VW1[lane];
    const float vb1s = VB1[0];

    __shared__ __align__(16) float xs[4][8][64];
    const int rowTile = (blockIdx.x*4 + wv)*8;

#pragma unroll
    for (int r = 0; r < 8; ++r) {
        int row = rowTile + r;
        int grow = (row < M) ? row : (M - 1);
        xs[wv][r][lane] = Xv[(size_t)grow*64 + lane];
    }
    __syncthreads();

    float ap[8], av[8];
#pragma unroll
    for (int r = 0; r < 8; ++r) { ap[r] = 0.f; av[r] = 0.f; }

#pragma unroll
    for (int k4 = 0; k4 < 16; ++k4) {
#pragma unroll
        for (int r = 0; r < 8; ++r) {
            float4 x4 = *(const float4*)&xs[wv][r][k4*4];
            ap[r] = fmaf(x4.x, wp[k4*4+0], ap[r]);
            ap[r] = fmaf(x4.y, wp[k4*4+1], ap[r]);
            ap[r] = fmaf(x4.z, wp[k4*4+2], ap[r]);
            ap[r] = fmaf(x4.w, wp[k4*4+3], ap[r]);
            av[r] = fmaf(x4.x, wq[k4*4+0], av[r]);
            av[r] = fmaf(x4.y, wq[k4*4+1], av[r]);
            av[r] = fmaf(x4.z, wq[k4*4+2], av[r]);
            av[r] = fmaf(x4.w, wq[k4*4+3], av[r]);
        }
    }

#pragma unroll
    for (int r = 0; r < 8; ++r) {
        float up = fmaxf(ap[r] + bp, 0.f) * pw1l;
        float uv = fmaxf(av[r] + bv, 0.f) * vw1l;
#pragma unroll
        for (int m = 32; m >= 1; m >>= 1) {
            up += __shfl_xor(up, m, 64);
            uv += __shfl_xor(uv, m, 64);
        }
        int row = rowTile + r;
        if (lane == 0 && row < M) {
            out[row]     = uv + vb1s;   // value
            out[M + row] = up;          // policy
        }
    }
}

// ---------------- host launch ----------------
extern "C" void kernel_launch(void* const* d_in, const int* in_sizes, int n_in,
                              void* d_out, int out_size, void* d_ws, size_t ws_size,
                              hipStream_t stream)
{
    const float* cf  = (const float*)d_in[0];
    const int*   ei  = (const int*)  d_in[1];
    const float* ef  = (const float*)d_in[2];
    const float* vf  = (const float*)d_in[3];

    const float* cw0 = (const float*)d_in[4];
    const float* cb0 = (const float*)d_in[5];
    const float* cw1 = (const float*)d_in[6];
    const float* cb1 = (const float*)d_in[7];
    const float* vw0 = (const float*)d_in[8];
    const float* vb0 = (const float*)d_in[9];
    const float* vw1 = (const float*)d_in[10];
    const float* vb1 = (const float*)d_in[11];

    const float* vc_lw  = (const float*)d_in[12];
    const float* vc_lb  = (const float*)d_in[13];
    const float* vc_ew  = (const float*)d_in[14];
    const float* vc_rw  = (const float*)d_in[15];
    const float* vc_fw  = (const float*)d_in[16];
    const float* vc_fb  = (const float*)d_in[17];
    const float* vc_ow0 = (const float*)d_in[18];
    const float* vc_ob0 = (const float*)d_in[19];
    const float* vc_ow1 = (const float*)d_in[20];
    const float* vc_ob1 = (const float*)d_in[21];

    const float* cv_lw  = (const float*)d_in[22];
    const float* cv_lb  = (const float*)d_in[23];
    const float* cv_ew  = (const float*)d_in[24];
    const float* cv_rw  = (const float*)d_in[25];
    const float* cv_fw  = (const float*)d_in[26];
    const float* cv_fb  = (const float*)d_in[27];
    const float* cv_ow0 = (const float*)d_in[28];
    const float* cv_ob0 = (const float*)d_in[29];
    const float* cv_ow1 = (const float*)d_in[30];
    const float* cv_ob1 = (const float*)d_in[31];

    const float* pw0  = (const float*)d_in[32];
    const float* pb0  = (const float*)d_in[33];
    const float* pw1  = (const float*)d_in[34];
    const float* vhw0 = (const float*)d_in[35];
    const float* vhb0 = (const float*)d_in[36];
    const float* vhw1 = (const float*)d_in[37];
    const float* vhb1 = (const float*)d_in[38];

    const int NC = in_sizes[0] / 5;
    const int E  = in_sizes[1] / 2;
    const int NV = in_sizes[3] / 19;

    // workspace layout (floats)
    float* ws = (float*)d_ws;
    const size_t CB = (size_t)NC * 64;
    const size_t VB = (size_t)NV * 64;
    float* CB0 = ws;            ws += CB;   // c0 -> c1
    float* CB1 = ws;            ws += CB;   // Rl_c -> agg_c -> Ls_c
    float* CB2 = ws;            ws += CB;   // aggpre_c -> u_c
    float* VB0 = ws;            ws += VB;   // v0 -> v1
    float* VB1 = ws;            ws += VB;   // Ls_v -> Rl_v -> agg_v
    float* VB2 = ws;            ws += VB;   // aggpre_v -> u_v
    float* degC = ws;           ws += NC;
    float* degV = ws;           ws += NV;

    const size_t need = ((3*CB + 3*VB) + NC + NV) * sizeof(float);
    if (ws_size < need) return;  // insufficient scratch: bail visibly

    // zero the accumulation buffers (poisoned 0xAA otherwise)
    hipMemsetAsync(CB2, 0, CB * sizeof(float), stream);
    hipMemsetAsync(VB2, 0, VB * sizeof(float), stream);
    hipMemsetAsync(degC, 0, NC * sizeof(float), stream);
    hipMemsetAsync(degV, 0, NV * sizeof(float), stream);

    dim3 blk(256);
    auto gridRows = [](int M) { return dim3((unsigned)((M + 31) / 32)); };
    dim3 gE((unsigned)(((size_t)E * 16 + 255) / 256));

    // embeddings
    emb_kernel<5> <<<gridRows(NC), blk, 0, stream>>>(cf, cw0, cb0, cw1, cb1, CB0, NC);
    emb_kernel<19><<<gridRows(NV), blk, 0, stream>>>(vf, vw0, vb0, vw1, vb1, VB0, NV);

    // ---- conv 1: v -> c  (dst = cons, src = var) ----
    lin64_kernel<false,1><<<gridRows(NC), blk, 0, stream>>>(CB0, vc_lw, vc_lb, nullptr, CB1, NC);  // Rl_c
    lin64_kernel<false,0><<<gridRows(NV), blk, 0, stream>>>(VB0, vc_rw, nullptr, nullptr, VB1, NV); // Ls_v
    edge_kernel<<<gE, blk, 0, stream>>>(ei, ei + E, ef, CB1, VB1, vc_ew, CB2, degC, E);
    lin64_kernel<false,2><<<gridRows(NC), blk, 0, stream>>>(CB2, vc_fw, vc_fb, degC, CB1, NC);      // agg_c
    lin128_kernel<true>  <<<gridRows(NC), blk, 0, stream>>>(CB1, CB0, vc_ow0, vc_ob0, CB2, NC);     // u_c
    lin64_kernel<false,1><<<gridRows(NC), blk, 0, stream>>>(CB2, vc_ow1, vc_ob1, nullptr, CB0, NC); // c1

    // ---- conv 2: c -> v  (dst = var, src = cons) ----
    lin64_kernel<false,1><<<gridRows(NV), blk, 0, stream>>>(VB0, cv_lw, cv_lb, nullptr, VB1, NV);   // Rl_v
    lin64_kernel<false,0><<<gridRows(NC), blk, 0, stream>>>(CB0, cv_rw, nullptr, nullptr, CB1, NC); // Ls_c
    edge_kernel<<<gE, blk, 0, stream>>>(ei + E, ei, ef, VB1, CB1, cv_ew, VB2, degV, E);
    lin64_kernel<false,2><<<gridRows(NV), blk, 0, stream>>>(VB2, cv_fw, cv_fb, degV, VB1, NV);      // agg_v
    lin128_kernel<true>  <<<gridRows(NV), blk, 0, stream>>>(VB1, VB0, cv_ow0, cv_ob0, VB2, NV);     // u_v
    lin64_kernel<false,1><<<gridRows(NV), blk, 0, stream>>>(VB2, cv_ow1, cv_ob1, nullptr, VB0, NV); // v1

    // ---- heads ----
    head_kernel<<<gridRows(NV), blk, 0, stream>>>(VB0, pw0, pb0, pw1, vhw0, vhb0, vhw1, vhb1,
                                                  (float*)d_out, NV);
}

// Round 2
// 5524.594 us; speedup vs baseline: 1.4461x; 1.4461x over previous
//
#include <hip/hip_runtime.h>

// ---------------- fused 2-layer embedding MLP ----------------
// Y = relu( relu(X@W0 + b0) @ W1 + b1 ),  X:[M,K0], W0:[K0,64], W1:[64,64]
template<int K0>
__global__ __launch_bounds__(256) void emb_kernel(
    const float* __restrict__ X,
    const float* __restrict__ W0, const float* __restrict__ B0,
    const float* __restrict__ W1, const float* __restrict__ B1,
    float* __restrict__ Y, int M)
{
    const int lane = threadIdx.x & 63;
    const int wv   = threadIdx.x >> 6;

    float w0[K0];
#pragma unroll
    for (int k = 0; k < K0; ++k) w0[k] = W0[k*64 + lane];
    float w1[64];
#pragma unroll
    for (int k = 0; k < 64; ++k) w1[k] = W1[k*64 + lane];
    const float b0 = B0[lane];
    const float b1 = B1[lane];

    __shared__ __align__(16) float xs[4][8*K0];
    __shared__ __align__(16) float hb[4][8][64];

    const int rowTile = (blockIdx.x*4 + wv)*8;
    for (int idx = lane; idx < 8*K0; idx += 64) {
        long gi = (long)rowTile*K0 + idx;
        xs[wv][idx] = (gi < (long)M*K0) ? X[gi] : 0.f;
    }
    __syncthreads();

#pragma unroll
    for (int r = 0; r < 8; ++r) {
        float acc = b0;
#pragma unroll
        for (int k = 0; k < K0; ++k) acc = fmaf(xs[wv][r*K0 + k], w0[k], acc);
        hb[wv][r][lane] = fmaxf(acc, 0.f);
    }
    __syncthreads();

#pragma unroll
    for (int r = 0; r < 8; ++r) {
        float acc = b1;
#pragma unroll
        for (int k4 = 0; k4 < 16; ++k4) {
            float4 h4 = *(const float4*)&hb[wv][r][k4*4];
            acc = fmaf(h4.x, w1[k4*4+0], acc);
            acc = fmaf(h4.y, w1[k4*4+1], acc);
            acc = fmaf(h4.z, w1[k4*4+2], acc);
            acc = fmaf(h4.w, w1[k4*4+3], acc);
        }
        int row = rowTile + r;
        if (row < M) Y[(size_t)row*64 + lane] = fmaxf(acc, 0.f);
    }
}

// ---------------- generic Y = act(X@W + bias) , K=64, N=64 ----------------
// BIAS: 0 = none, 1 = +b[n], 2 = +b[n]*deg[row] where deg = rowoff[r+1]-rowoff[r]
// In-place (Y == X) is safe: rows are staged to LDS (barrier) before any write,
// and each row is read/written only by the block that owns it.
template<bool RELU, int BIAS>
__global__ __launch_bounds__(256) void lin64_kernel(
    const float* __restrict__ X, const float* __restrict__ W,
    const float* __restrict__ bias, const int* __restrict__ rowoff,
    float* Y, int M)
{
    const int lane = threadIdx.x & 63;
    const int wv   = threadIdx.x >> 6;

    float w[64];
#pragma unroll
    for (int k = 0; k < 64; ++k) w[k] = W[k*64 + lane];
    const float bb = (BIAS >= 1) ? bias[lane] : 0.f;

    __shared__ __align__(16) float xs[4][8][64];
    const int rowTile = (blockIdx.x*4 + wv)*8;

#pragma unroll
    for (int r = 0; r < 8; ++r) {
        int row = rowTile + r;
        int grow = (row < M) ? row : (M - 1);
        xs[wv][r][lane] = X[(size_t)grow*64 + lane];
    }
    __syncthreads();

    float acc[8];
#pragma unroll
    for (int r = 0; r < 8; ++r) acc[r] = 0.f;

#pragma unroll
    for (int k4 = 0; k4 < 16; ++k4) {
#pragma unroll
        for (int r = 0; r < 8; ++r) {
            float4 x4 = *(const float4*)&xs[wv][r][k4*4];
            acc[r] = fmaf(x4.x, w[k4*4+0], acc[r]);
            acc[r] = fmaf(x4.y, w[k4*4+1], acc[r]);
            acc[r] = fmaf(x4.z, w[k4*4+2], acc[r]);
            acc[r] = fmaf(x4.w, w[k4*4+3], acc[r]);
        }
    }

#pragma unroll
    for (int r = 0; r < 8; ++r) {
        int row = rowTile + r;
        if (row >= M) continue;
        float v = acc[r];
        if (BIAS == 1) v += bb;
        if (BIAS == 2) v += bb * (float)(rowoff[row + 1] - rowoff[row]);
        if (RELU) v = fmaxf(v, 0.f);
        Y[(size_t)row*64 + lane] = v;
    }
}

// ---------------- Y = act( concat(X1,X2) @ W + b ) , K=128, N=64 ----------------
// In-place over X1 is safe (same LDS-staging argument).
template<bool RELU>
__global__ __launch_bounds__(256) void lin128_kernel(
    const float* __restrict__ X1, const float* __restrict__ X2,
    const float* __restrict__ W /*[128][64]*/, const float* __restrict__ bias,
    float* Y, int M)
{
    const int lane = threadIdx.x & 63;
    const int wv   = threadIdx.x >> 6;

    __shared__ __align__(16) float xs[4][8][128];
    const int rowTile = (blockIdx.x*4 + wv)*8;

#pragma unroll
    for (int r = 0; r < 8; ++r) {
        int row = rowTile + r;
        int grow = (row < M) ? row : (M - 1);
        xs[wv][r][lane]      = X1[(size_t)grow*64 + lane];
        xs[wv][r][64 + lane] = X2[(size_t)grow*64 + lane];
    }
    __syncthreads();

    float acc[8];
#pragma unroll
    for (int r = 0; r < 8; ++r) acc[r] = 0.f;

    float w[64];
#pragma unroll
    for (int k = 0; k < 64; ++k) w[k] = W[k*64 + lane];
#pragma unroll
    for (int k4 = 0; k4 < 16; ++k4) {
#pragma unroll
        for (int r = 0; r < 8; ++r) {
            float4 x4 = *(const float4*)&xs[wv][r][k4*4];
            acc[r] = fmaf(x4.x, w[k4*4+0], acc[r]);
            acc[r] = fmaf(x4.y, w[k4*4+1], acc[r]);
            acc[r] = fmaf(x4.z, w[k4*4+2], acc[r]);
            acc[r] = fmaf(x4.w, w[k4*4+3], acc[r]);
        }
    }
#pragma unroll
    for (int k = 0; k < 64; ++k) w[k] = W[(64 + k)*64 + lane];
#pragma unroll
    for (int k4 = 0; k4 < 16; ++k4) {
#pragma unroll
        for (int r = 0; r < 8; ++r) {
            float4 x4 = *(const float4*)&xs[wv][r][64 + k4*4];
            acc[r] = fmaf(x4.x, w[k4*4+0], acc[r]);
            acc[r] = fmaf(x4.y, w[k4*4+1], acc[r]);
            acc[r] = fmaf(x4.z, w[k4*4+2], acc[r]);
            acc[r] = fmaf(x4.w, w[k4*4+3], acc[r]);
        }
    }

    const float bb = bias[lane];
#pragma unroll
    for (int r = 0; r < 8; ++r) {
        int row = rowTile + r;
        if (row >= M) continue;
        float v = acc[r] + bb;
        if (RELU) v = fmaxf(v, 0.f);
        Y[(size_t)row*64 + lane] = v;
    }
}

// ---------------- counting-sort machinery ----------------

__global__ __launch_bounds__(256) void hist2_kernel(
    const int* __restrict__ eic, const int* __restrict__ eiv,
    int* cntC, int* cntV, int E)
{
    int e = blockIdx.x*256 + threadIdx.x;
    if (e >= E) return;
    atomicAdd(&cntC[eic[e]], 1);
    atomicAdd(&cntV[eiv[e]], 1);
}

// per-1024-chunk sums
__global__ __launch_bounds__(256) void scan1_kernel(const int* __restrict__ in, int* bs, int N)
{
    __shared__ int sm[256];
    const int t = threadIdx.x;
    const int base = blockIdx.x*1024 + t*4;
    int s = 0;
#pragma unroll
    for (int i = 0; i < 4; ++i) { int idx = base + i; if (idx < N) s += in[idx]; }
    sm[t] = s; __syncthreads();
    for (int d = 128; d > 0; d >>= 1) { if (t < d) sm[t] += sm[t + d]; __syncthreads(); }
    if (t == 0) bs[blockIdx.x] = sm[0];
}

// exclusive scan of up-to-1024 block sums, single block
__global__ __launch_bounds__(256) void scan2_kernel(const int* __restrict__ bs, int* bsex, int nb)
{
    __shared__ int sm[1024];
    for (int i = threadIdx.x; i < nb; i += 256) sm[i] = bs[i];
    __syncthreads();
    if (threadIdx.x == 0) { int a = 0; for (int i = 0; i < nb; ++i) { int v = sm[i]; sm[i] = a; a += v; } }
    __syncthreads();
    for (int i = threadIdx.x; i < nb; i += 256) bsex[i] = sm[i];
}

// final exclusive offsets; also writes out[N] = total
__global__ __launch_bounds__(256) void scan3_kernel(
    const int* __restrict__ in, const int* __restrict__ bsex, int* out, int N)
{
    __shared__ int sm[256];
    const int t = threadIdx.x;
    const int base = blockIdx.x*1024 + t*4;
    int v[4]; int s = 0;
#pragma unroll
    for (int i = 0; i < 4; ++i) { int idx = base + i; v[i] = (idx < N) ? in[idx] : 0; s += v[i]; }
    sm[t] = s; __syncthreads();
    int x = s;
    for (int d = 1; d < 256; d <<= 1) {
        int y = (t >= d) ? sm[t - d] : 0;
        __syncthreads();
        x += y; sm[t] = x;
        __syncthreads();
    }
    int off0 = bsex[blockIdx.x] + (x - s);
#pragma unroll
    for (int i = 0; i < 4; ++i) {
        int idx = base + i;
        if (idx < N) {
            out[idx] = off0;
            off0 += v[i];
            if (idx == N - 1) out[N] = off0;
        }
    }
}

// scatter edges into both dst-sorted buckets; rec = {src as int bits, ef}
__global__ __launch_bounds__(256) void scatter2_kernel(
    const int* __restrict__ eic, const int* __restrict__ eiv,
    const float* __restrict__ ef,
    int* curC, int* curV, float2* bC, float2* bV, int E)
{
    int e = blockIdx.x*256 + threadIdx.x;
    if (e >= E) return;
    const int c = eic[e], v = eiv[e];
    const float f = ef[e];
    int pc = atomicAdd(&curC[c], 1);
    bC[pc] = make_float2(__int_as_float(v), f);
    int pv = atomicAdd(&curV[v], 1);
    bV[pv] = make_float2(__int_as_float(c), f);
}

// ---------------- bucketed aggregation ----------------
// One wave per dst node, lane = feature.
// out[node] = sum_{edges e with dst==node} relu(Rl[node] + Ls[src(e)] + ef(e)*ew)
// out may alias Rl (row read once at start, written once at end, per-wave owned).
__global__ __launch_bounds__(256) void agg_kernel(
    const int* __restrict__ off, const float2* __restrict__ bucket,
    const float* Rl, const float* __restrict__ Ls,
    const float* __restrict__ ew, float* out, int N)
{
    const int node = blockIdx.x*4 + (threadIdx.x >> 6);
    if (node >= N) return;
    const int lane = threadIdx.x & 63;

    const int s0 = off[node];
    const int e0 = off[node + 1];
    const float rl = Rl[(size_t)node*64 + lane];
    const float w  = ew[lane];

    float acc = 0.f;
    int j = s0;
    for (; j + 1 < e0; j += 2) {
        float2 r0 = bucket[j];
        float2 r1 = bucket[j + 1];
        float ls0 = Ls[(size_t)__float_as_int(r0.x)*64 + lane];
        float ls1 = Ls[(size_t)__float_as_int(r1.x)*64 + lane];
        acc += fmaxf(rl + ls0 + r0.y*w, 0.f);
        acc += fmaxf(rl + ls1 + r1.y*w, 0.f);
    }
    if (j < e0) {
        float2 r0 = bucket[j];
        float ls0 = Ls[(size_t)__float_as_int(r0.x)*64 + lane];
        acc += fmaxf(rl + ls0 + r0.y*w, 0.f);
    }
    out[(size_t)node*64 + lane] = acc;
}

// ---------------- fused heads: value & policy ----------------
__global__ __launch_bounds__(256) void head_kernel(
    const float* __restrict__ Xv,
    const float* __restrict__ PW0, const float* __restrict__ PB0, const float* __restrict__ PW1,
    const float* __restrict__ VW0, const float* __restrict__ VB0, const float* __restrict__ VW1,
    const float* __restrict__ VB1,
    float* __restrict__ out, int M)
{
    const int lane = threadIdx.x & 63;
    const int wv   = threadIdx.x >> 6;

    float wp[64], wq[64];
#pragma unroll
    for (int k = 0; k < 64; ++k) { wp[k] = PW0[k*64 + lane]; wq[k] = VW0[k*64 + lane]; }
    const float bp = PB0[lane];
    const float bv = VB0[lane];
    const float pw1l = PW1[lane];
    const float vw1l = VW1[lane];
    const float vb1s = VB1[0];

    __shared__ __align__(16) float xs[4][8][64];
    const int rowTile = (blockIdx.x*4 + wv)*8;

#pragma unroll
    for (int r = 0; r < 8; ++r) {
        int row = rowTile + r;
        int grow = (row < M) ? row : (M - 1);
        xs[wv][r][lane] = Xv[(size_t)grow*64 + lane];
    }
    __syncthreads();

    float ap[8], av[8];
#pragma unroll
    for (int r = 0; r < 8; ++r) { ap[r] = 0.f; av[r] = 0.f; }

#pragma unroll
    for (int k4 = 0; k4 < 16; ++k4) {
#pragma unroll
        for (int r = 0; r < 8; ++r) {
            float4 x4 = *(const float4*)&xs[wv][r][k4*4];
            ap[r] = fmaf(x4.x, wp[k4*4+0], ap[r]);
            ap[r] = fmaf(x4.y, wp[k4*4+1], ap[r]);
            ap[r] = fmaf(x4.z, wp[k4*4+2], ap[r]);
            ap[r] = fmaf(x4.w, wp[k4*4+3], ap[r]);
            av[r] = fmaf(x4.x, wq[k4*4+0], av[r]);
            av[r] = fmaf(x4.y, wq[k4*4+1], av[r]);
            av[r] = fmaf(x4.z, wq[k4*4+2], av[r]);
            av[r] = fmaf(x4.w, wq[k4*4+3], av[r]);
        }
    }

#pragma unroll
    for (int r = 0; r < 8; ++r) {
        float up = fmaxf(ap[r] + bp, 0.f) * pw1l;
        float uv = fmaxf(av[r] + bv, 0.f) * vw1l;
#pragma unroll
        for (int m = 32; m >= 1; m >>= 1) {
            up += __shfl_xor(up, m, 64);
            uv += __shfl_xor(uv, m, 64);
        }
        int row = rowTile + r;
        if (lane == 0 && row < M) {
            out[row]     = uv + vb1s;   // value
            out[M + row] = up;          // policy
        }
    }
}

// ---------------- host launch ----------------
extern "C" void kernel_launch(void* const* d_in, const int* in_sizes, int n_in,
                              void* d_out, int out_size, void* d_ws, size_t ws_size,
                              hipStream_t stream)
{
    const float* cf  = (const float*)d_in[0];
    const int*   ei  = (const int*)  d_in[1];
    const float* ef  = (const float*)d_in[2];
    const float* vf  = (const float*)d_in[3];

    const float* cw0 = (const float*)d_in[4];
    const float* cb0 = (const float*)d_in[5];
    const float* cw1 = (const float*)d_in[6];
    const float* cb1 = (const float*)d_in[7];
    const float* vw0 = (const float*)d_in[8];
    const float* vb0 = (const float*)d_in[9];
    const float* vw1 = (const float*)d_in[10];
    const float* vb1 = (const float*)d_in[11];

    const float* vc_lw  = (const float*)d_in[12];
    const float* vc_lb  = (const float*)d_in[13];
    const float* vc_ew  = (const float*)d_in[14];
    const float* vc_rw  = (const float*)d_in[15];
    const float* vc_fw  = (const float*)d_in[16];
    const float* vc_fb  = (const float*)d_in[17];
    const float* vc_ow0 = (const float*)d_in[18];
    const float* vc_ob0 = (const float*)d_in[19];
    const float* vc_ow1 = (const float*)d_in[20];
    const float* vc_ob1 = (const float*)d_in[21];

    const float* cv_lw  = (const float*)d_in[22];
    const float* cv_lb  = (const float*)d_in[23];
    const float* cv_ew  = (const float*)d_in[24];
    const float* cv_rw  = (const float*)d_in[25];
    const float* cv_fw  = (const float*)d_in[26];
    const float* cv_fb  = (const float*)d_in[27];
    const float* cv_ow0 = (const float*)d_in[28];
    const float* cv_ob0 = (const float*)d_in[29];
    const float* cv_ow1 = (const float*)d_in[30];
    const float* cv_ob1 = (const float*)d_in[31];

    const float* pw0  = (const float*)d_in[32];
    const float* pb0  = (const float*)d_in[33];
    const float* pw1  = (const float*)d_in[34];
    const float* vhw0 = (const float*)d_in[35];
    const float* vhb0 = (const float*)d_in[36];
    const float* vhw1 = (const float*)d_in[37];
    const float* vhb1 = (const float*)d_in[38];

    const int NC = in_sizes[0] / 5;
    const int E  = in_sizes[1] / 2;
    const int NV = in_sizes[3] / 19;

    // ---- workspace layout ----
    const size_t CBsz = (size_t)NC * 64;
    const size_t VBsz = (size_t)NV * 64;
    float* ws = (float*)d_ws;
    float* CB0 = ws;  ws += CBsz;
    float* CB1 = ws;  ws += CBsz;
    float* VB0 = ws;  ws += VBsz;
    float* VB1 = ws;  ws += VBsz;
    float2* bC = (float2*)ws;  ws += 2*(size_t)E;
    float2* bV = (float2*)ws;  ws += 2*(size_t)E;
    int* cntC = (int*)ws;  ws += NC;
    int* offC = (int*)ws;  ws += NC + 1;
    int* cntV = (int*)ws;  ws += NV;
    int* offV = (int*)ws;  ws += NV + 1;
    int* bs   = (int*)ws;  ws += 1024;
    int* bsex = (int*)ws;  ws += 1024;

    const size_t need = (size_t)((float*)ws - (float*)d_ws) * sizeof(float);
    if (ws_size < need) return;

    dim3 blk(256);
    auto gridRows = [](int M) { return dim3((unsigned)((M + 31) / 32)); };
    auto gridNode = [](int M) { return dim3((unsigned)((M + 3) / 4)); };
    dim3 gE((unsigned)((E + 255) / 256));
    const int nbC = (NC + 1023) / 1024;
    const int nbV = (NV + 1023) / 1024;

    const int* eic = ei;        // edge cons index
    const int* eiv = ei + E;    // edge var index

    // ---- counting sort of edges by destination (both directions) ----
    hipMemsetAsync(cntC, 0, (size_t)NC * sizeof(int), stream);
    hipMemsetAsync(cntV, 0, (size_t)NV * sizeof(int), stream);
    hist2_kernel<<<gE, blk, 0, stream>>>(eic, eiv, cntC, cntV, E);
    scan1_kernel<<<dim3(nbC), blk, 0, stream>>>(cntC, bs, NC);
    scan2_kernel<<<dim3(1),  blk, 0, stream>>>(bs, bsex, nbC);
    scan3_kernel<<<dim3(nbC), blk, 0, stream>>>(cntC, bsex, offC, NC);
    scan1_kernel<<<dim3(nbV), blk, 0, stream>>>(cntV, bs, NV);
    scan2_kernel<<<dim3(1),  blk, 0, stream>>>(bs, bsex, nbV);
    scan3_kernel<<<dim3(nbV), blk, 0, stream>>>(cntV, bsex, offV, NV);
    hipMemcpyAsync(cntC, offC, (size_t)NC * sizeof(int), hipMemcpyDeviceToDevice, stream);
    hipMemcpyAsync(cntV, offV, (size_t)NV * sizeof(int), hipMemcpyDeviceToDevice, stream);
    scatter2_kernel<<<gE, blk, 0, stream>>>(eic, eiv, ef, cntC, cntV, bC, bV, E);

    // ---- embeddings ----
    emb_kernel<5> <<<gridRows(NC), blk, 0, stream>>>(cf, cw0, cb0, cw1, cb1, CB0, NC);
    emb_kernel<19><<<gridRows(NV), blk, 0, stream>>>(vf, vw0, vb0, vw1, vb1, VB0, NV);

    // ---- conv 1: v -> c  (dst = cons, src = var) ----
    lin64_kernel<false,1><<<gridRows(NC), blk, 0, stream>>>(CB0, vc_lw, vc_lb, nullptr, CB1, NC);   // Rl_c
    lin64_kernel<false,0><<<gridRows(NV), blk, 0, stream>>>(VB0, vc_rw, nullptr, nullptr, VB1, NV); // Ls_v
    agg_kernel<<<gridNode(NC), blk, 0, stream>>>(offC, bC, CB1, VB1, vc_ew, CB1, NC);               // aggpre_c (in-place)
    lin64_kernel<false,2><<<gridRows(NC), blk, 0, stream>>>(CB1, vc_fw, vc_fb, offC, CB1, NC);      // agg_c (in-place)
    lin128_kernel<true>  <<<gridRows(NC), blk, 0, stream>>>(CB1, CB0, vc_ow0, vc_ob0, CB1, NC);     // u_c (in-place)
    lin64_kernel<false,1><<<gridRows(NC), blk, 0, stream>>>(CB1, vc_ow1, vc_ob1, nullptr, CB0, NC); // c1

    // ---- conv 2: c -> v  (dst = var, src = cons) ----
    lin64_kernel<false,1><<<gridRows(NV), blk, 0, stream>>>(VB0, cv_lw, cv_lb, nullptr, VB1, NV);   // Rl_v
    lin64_kernel<false,0><<<gridRows(NC), blk, 0, stream>>>(CB0, cv_rw, nullptr, nullptr, CB1, NC); // Ls_c
    agg_kernel<<<gridNode(NV), blk, 0, stream>>>(offV, bV, VB1, CB1, cv_ew, VB1, NV);               // aggpre_v (in-place)
    lin64_kernel<false,2><<<gridRows(NV), blk, 0, stream>>>(VB1, cv_fw, cv_fb, offV, VB1, NV);      // agg_v (in-place)
    lin128_kernel<true>  <<<gridRows(NV), blk, 0, stream>>>(VB1, VB0, cv_ow0, cv_ob0, VB1, NV);     // u_v (in-place)
    lin64_kernel<false,1><<<gridRows(NV), blk, 0, stream>>>(VB1, cv_ow1, cv_ob1, nullptr, VB0, NV); // v1

    // ---- heads ----
    head_kernel<<<gridRows(NV), blk, 0, stream>>>(VB0, pw0, pb0, pw1, vhw0, vhb0, vhw1, vhb1,
                                                  (float*)d_out, NV);
}

// Round 5
// 1148.631 us; speedup vs baseline: 6.9554x; 4.8097x over previous
//
#include <hip/hip_runtime.h>

typedef unsigned short u16;

__device__ __forceinline__ float bf2f(u16 u) {
    return __uint_as_float(((unsigned int)u) << 16);
}
__device__ __forceinline__ u16 f2bf(float f) {
    unsigned int x = __float_as_uint(f);
    return (u16)((x + 0x7fffu + ((x >> 16) & 1u)) >> 16);
}

// =============== on-device weight prep (algebraic collapse) ===============
// Fc  = vc_fw @ ow0A            gc  = vc_fb @ ow0A
// Hc  = vc_ow1 @ cv_rw          hc  = vc_ob1 @ cv_rw
// Fv  = cv_fw @ cv_ow0A         gv  = cv_fb @ cv_ow0A
// Pw  = cv_ow1 @ pw0            pbp = cv_ob1 @ pw0 + pb0
// Vw  = cv_ow1 @ vhw0           vbp = cv_ob1 @ vhw0 + vhb0

__device__ __forceinline__ void mm64(const float* A, const float* B, float* C, int lane)
{
    float bcol[64];
#pragma unroll
    for (int m = 0; m < 64; ++m) bcol[m] = B[m*64 + lane];
    for (int k = 0; k < 64; ++k) {
        float acc = 0.f;
#pragma unroll
        for (int m = 0; m < 64; ++m) acc = fmaf(A[k*64 + m], bcol[m], acc);
        C[k*64 + lane] = acc;
    }
}

__device__ __forceinline__ void vm64(const float* a, const float* B, const float* add,
                                     float* c, int lane)
{
    float acc = (add != 0) ? add[lane] : 0.f;
#pragma unroll
    for (int m = 0; m < 64; ++m) acc = fmaf(a[m], B[m*64 + lane], acc);
    c[lane] = acc;
}

__global__ __launch_bounds__(256) void prep_kernel(
    const float* vc_fw, const float* vc_fb, const float* vc_ow0,
    const float* vc_ow1, const float* vc_ob1,
    const float* cv_rw, const float* cv_fw, const float* cv_fb,
    const float* cv_ow0, const float* cv_ow1, const float* cv_ob1,
    const float* pw0, const float* pb0, const float* vhw0, const float* vhb0,
    float* Fc, float* gc, float* Hc, float* hc, float* Fv, float* gv,
    float* Pw, float* pbp, float* Vw, float* vbp)
{
    const int wv = threadIdx.x >> 6;
    const int lane = threadIdx.x & 63;
    if (wv == 0) {
        mm64(vc_fw, vc_ow0, Fc, lane);
        vm64(vc_fb, vc_ow0, 0, gc, lane);
    } else if (wv == 1) {
        mm64(vc_ow1, cv_rw, Hc, lane);
        vm64(vc_ob1, cv_rw, 0, hc, lane);
    } else if (wv == 2) {
        mm64(cv_fw, cv_ow0, Fv, lane);
        vm64(cv_fb, cv_ow0, 0, gv, lane);
    } else {
        mm64(cv_ow1, pw0, Pw, lane);
        vm64(cv_ob1, pw0, pb0, pbp, lane);
        mm64(cv_ow1, vhw0, Vw, lane);
        vm64(cv_ob1, vhw0, vhb0, vbp, lane);
    }
}

// =============== embeddings (fused with downstream per-node linears) ===============
// embC: c0 = emb(cf) -> bf16; Rl_c = c0@vc_lw + vc_lb -> f32
__global__ __launch_bounds__(256) void embc_kernel(
    const float* __restrict__ X,
    const float* __restrict__ W0, const float* __restrict__ B0,
    const float* __restrict__ W1, const float* __restrict__ B1,
    const float* __restrict__ LW, const float* __restrict__ LB,
    u16* __restrict__ c0out, float* __restrict__ RlOut, int M)
{
    const int lane = threadIdx.x & 63;
    const int wv   = threadIdx.x >> 6;
    __shared__ __align__(16) float xs[4][8*5];
    __shared__ __align__(16) float hb[4][8][64];
    __shared__ __align__(16) float yb[4][8][64];
    const int rowTile = (blockIdx.x*4 + wv)*8;

    for (int idx = lane; idx < 8*5; idx += 64) {
        long gi = (long)rowTile*5 + idx;
        xs[wv][idx] = (gi < (long)M*5) ? X[gi] : 0.f;
    }
    {
        float w0[5];
#pragma unroll
        for (int k = 0; k < 5; ++k) w0[k] = W0[k*64 + lane];
        const float b0 = B0[lane];
#pragma unroll
        for (int r = 0; r < 8; ++r) {
            float acc = b0;
#pragma unroll
            for (int k = 0; k < 5; ++k) acc = fmaf(xs[wv][r*5 + k], w0[k], acc);
            hb[wv][r][lane] = fmaxf(acc, 0.f);
        }
    }
    {
        float w1[64];
#pragma unroll
        for (int k = 0; k < 64; ++k) w1[k] = W1[k*64 + lane];
        const float b1 = B1[lane];
#pragma unroll
        for (int r = 0; r < 8; ++r) {
            float acc = b1;
#pragma unroll
            for (int k4 = 0; k4 < 16; ++k4) {
                float4 h4 = *(const float4*)&hb[wv][r][k4*4];
                acc = fmaf(h4.x, w1[k4*4+0], acc);
                acc = fmaf(h4.y, w1[k4*4+1], acc);
                acc = fmaf(h4.z, w1[k4*4+2], acc);
                acc = fmaf(h4.w, w1[k4*4+3], acc);
            }
            float y = fmaxf(acc, 0.f);
            yb[wv][r][lane] = y;
            int row = rowTile + r;
            if (row < M) c0out[(size_t)row*64 + lane] = f2bf(y);
        }
    }
    {
        float w[64];
#pragma unroll
        for (int k = 0; k < 64; ++k) w[k] = LW[k*64 + lane];
        const float bb = LB[lane];
#pragma unroll
        for (int r = 0; r < 8; ++r) {
            float acc = bb;
#pragma unroll
            for (int k4 = 0; k4 < 16; ++k4) {
                float4 y4 = *(const float4*)&yb[wv][r][k4*4];
                acc = fmaf(y4.x, w[k4*4+0], acc);
                acc = fmaf(y4.y, w[k4*4+1], acc);
                acc = fmaf(y4.z, w[k4*4+2], acc);
                acc = fmaf(y4.w, w[k4*4+3], acc);
            }
            int row = rowTile + r;
            if (row < M) RlOut[(size_t)row*64 + lane] = acc;
        }
    }
}

// embV: v0 = emb(vf) -> bf16; Ls_v = v0@vc_rw -> bf16; Rl_v = v0@cv_lw+cv_lb -> f32
__global__ __launch_bounds__(256) void embv_kernel(
    const float* __restrict__ X,
    const float* __restrict__ W0, const float* __restrict__ B0,
    const float* __restrict__ W1, const float* __restrict__ B1,
    const float* __restrict__ RW,
    const float* __restrict__ LW, const float* __restrict__ LB,
    u16* __restrict__ v0out, u16* __restrict__ LsOut,
    float* __restrict__ RlOut, int M)
{
    const int lane = threadIdx.x & 63;
    const int wv   = threadIdx.x >> 6;
    __shared__ __align__(16) float xs[4][8*19];
    __shared__ __align__(16) float hb[4][8][64];
    __shared__ __align__(16) float yb[4][8][64];
    const int rowTile = (blockIdx.x*4 + wv)*8;

    for (int idx = lane; idx < 8*19; idx += 64) {
        long gi = (long)rowTile*19 + idx;
        xs[wv][idx] = (gi < (long)M*19) ? X[gi] : 0.f;
    }
    {
        float w0[19];
#pragma unroll
        for (int k = 0; k < 19; ++k) w0[k] = W0[k*64 + lane];
        const float b0 = B0[lane];
#pragma unroll
        for (int r = 0; r < 8; ++r) {
            float acc = b0;
#pragma unroll
            for (int k = 0; k < 19; ++k) acc = fmaf(xs[wv][r*19 + k], w0[k], acc);
            hb[wv][r][lane] = fmaxf(acc, 0.f);
        }
    }
    {
        float w1[64];
#pragma unroll
        for (int k = 0; k < 64; ++k) w1[k] = W1[k*64 + lane];
        const float b1 = B1[lane];
#pragma unroll
        for (int r = 0; r < 8; ++r) {
            float acc = b1;
#pragma unroll
            for (int k4 = 0; k4 < 16; ++k4) {
                float4 h4 = *(const float4*)&hb[wv][r][k4*4];
                acc = fmaf(h4.x, w1[k4*4+0], acc);
                acc = fmaf(h4.y, w1[k4*4+1], acc);
                acc = fmaf(h4.z, w1[k4*4+2], acc);
                acc = fmaf(h4.w, w1[k4*4+3], acc);
            }
            float y = fmaxf(acc, 0.f);
            yb[wv][r][lane] = y;
            int row = rowTile + r;
            if (row < M) v0out[(size_t)row*64 + lane] = f2bf(y);
        }
    }
    {
        float w[64];
#pragma unroll
        for (int k = 0; k < 64; ++k) w[k] = RW[k*64 + lane];
#pragma unroll
        for (int r = 0; r < 8; ++r) {
            float acc = 0.f;
#pragma unroll
            for (int k4 = 0; k4 < 16; ++k4) {
                float4 y4 = *(const float4*)&yb[wv][r][k4*4];
                acc = fmaf(y4.x, w[k4*4+0], acc);
                acc = fmaf(y4.y, w[k4*4+1], acc);
                acc = fmaf(y4.z, w[k4*4+2], acc);
                acc = fmaf(y4.w, w[k4*4+3], acc);
            }
            int row = rowTile + r;
            if (row < M) LsOut[(size_t)row*64 + lane] = f2bf(acc);
        }
    }
    {
        float w[64];
#pragma unroll
        for (int k = 0; k < 64; ++k) w[k] = LW[k*64 + lane];
        const float bb = LB[lane];
#pragma unroll
        for (int r = 0; r < 8; ++r) {
            float acc = bb;
#pragma unroll
            for (int k4 = 0; k4 < 16; ++k4) {
                float4 y4 = *(const float4*)&yb[wv][r][k4*4];
                acc = fmaf(y4.x, w[k4*4+0], acc);
                acc = fmaf(y4.y, w[k4*4+1], acc);
                acc = fmaf(y4.z, w[k4*4+2], acc);
                acc = fmaf(y4.w, w[k4*4+3], acc);
            }
            int row = rowTile + r;
            if (row < M) RlOut[(size_t)row*64 + lane] = acc;
        }
    }
}

// =============== counting sort ===============
__global__ __launch_bounds__(256) void hist2_kernel(
    const int* __restrict__ eic, const int* __restrict__ eiv,
    int* cntC, int* cntV, int E)
{
    int e = blockIdx.x*256 + threadIdx.x;
    if (e >= E) return;
    atomicAdd(&cntC[eic[e]], 1);
    atomicAdd(&cntV[eiv[e]], 1);
}

__global__ __launch_bounds__(256) void scan1_kernel(const int* __restrict__ in, int* blks, int N)
{
    __shared__ int sm[256];
    const int t = threadIdx.x;
    const int base = blockIdx.x*1024 + t*4;
    int s = 0;
#pragma unroll
    for (int i = 0; i < 4; ++i) { int idx = base + i; if (idx < N) s += in[idx]; }
    sm[t] = s; __syncthreads();
    for (int d = 128; d > 0; d >>= 1) { if (t < d) sm[t] += sm[t + d]; __syncthreads(); }
    if (t == 0) blks[blockIdx.x] = sm[0];
}

__global__ __launch_bounds__(256) void scan2_kernel(const int* __restrict__ blks, int* blkex, int nb)
{
    __shared__ int sm[1024];
    for (int i = threadIdx.x; i < nb; i += 256) sm[i] = blks[i];
    __syncthreads();
    if (threadIdx.x == 0) { int a = 0; for (int i = 0; i < nb; ++i) { int v = sm[i]; sm[i] = a; a += v; } }
    __syncthreads();
    for (int i = threadIdx.x; i < nb; i += 256) blkex[i] = sm[i];
}

__global__ __launch_bounds__(256) void scan3_kernel(
    const int* __restrict__ in, const int* __restrict__ blkex, int* out, int N)
{
    __shared__ int sm[256];
    const int t = threadIdx.x;
    const int base = blockIdx.x*1024 + t*4;
    int v[4]; int s = 0;
#pragma unroll
    for (int i = 0; i < 4; ++i) { int idx = base + i; v[i] = (idx < N) ? in[idx] : 0; s += v[i]; }
    sm[t] = s; __syncthreads();
    int x = s;
    for (int d = 1; d < 256; d <<= 1) {
        int y = (t >= d) ? sm[t - d] : 0;
        __syncthreads();
        x += y; sm[t] = x;
        __syncthreads();
    }
    int off0 = blkex[blockIdx.x] + (x - s);
#pragma unroll
    for (int i = 0; i < 4; ++i) {
        int idx = base + i;
        if (idx < N) {
            out[idx] = off0;
            off0 += v[i];
            if (idx == N - 1) out[N] = off0;
        }
    }
}

// scatter one direction: bucket[pos] = {src_bits, ef}
__global__ __launch_bounds__(256) void scatter1_kernel(
    const int* __restrict__ dIdx, const int* __restrict__ sIdx,
    const float* __restrict__ ef, int* cur, float2* __restrict__ bucket, int E)
{
    int e = blockIdx.x*256 + threadIdx.x;
    if (e >= E) return;
    int d = dIdx[e];
    int pos = atomicAdd(&cur[d], 1);
    bucket[pos] = make_float2(__int_as_float(sIdx[e]), ef[e]);
}

// =============== bucketed aggregation, 8-deep gather pipeline ===============
__global__ __launch_bounds__(256) void agg_kernel(
    const int* __restrict__ off, const float2* __restrict__ bucket,
    float* RlA, const u16* __restrict__ Lsb,
    const float* __restrict__ ew, int N)
{
    const int node = blockIdx.x*4 + (threadIdx.x >> 6);
    if (node >= N) return;
    const int lane = threadIdx.x & 63;
    const int s0 = off[node];
    const int e1 = off[node + 1];
    const float rl = RlA[(size_t)node*64 + lane];
    const float w  = ew[lane];

    float acc = 0.f;
    int j = s0;
    for (; j + 8 <= e1; j += 8) {
        float2 q0 = bucket[j+0], q1 = bucket[j+1], q2 = bucket[j+2], q3 = bucket[j+3];
        float2 q4 = bucket[j+4], q5 = bucket[j+5], q6 = bucket[j+6], q7 = bucket[j+7];
        float l0 = bf2f(Lsb[(size_t)__float_as_int(q0.x)*64 + lane]);
        float l1 = bf2f(Lsb[(size_t)__float_as_int(q1.x)*64 + lane]);
        float l2 = bf2f(Lsb[(size_t)__float_as_int(q2.x)*64 + lane]);
        float l3 = bf2f(Lsb[(size_t)__float_as_int(q3.x)*64 + lane]);
        float l4 = bf2f(Lsb[(size_t)__float_as_int(q4.x)*64 + lane]);
        float l5 = bf2f(Lsb[(size_t)__float_as_int(q5.x)*64 + lane]);
        float l6 = bf2f(Lsb[(size_t)__float_as_int(q6.x)*64 + lane]);
        float l7 = bf2f(Lsb[(size_t)__float_as_int(q7.x)*64 + lane]);
        acc += fmaxf(fmaf(q0.y, w, rl + l0), 0.f);
        acc += fmaxf(fmaf(q1.y, w, rl + l1), 0.f);
        acc += fmaxf(fmaf(q2.y, w, rl + l2), 0.f);
        acc += fmaxf(fmaf(q3.y, w, rl + l3), 0.f);
        acc += fmaxf(fmaf(q4.y, w, rl + l4), 0.f);
        acc += fmaxf(fmaf(q5.y, w, rl + l5), 0.f);
        acc += fmaxf(fmaf(q6.y, w, rl + l6), 0.f);
        acc += fmaxf(fmaf(q7.y, w, rl + l7), 0.f);
    }
    for (; j < e1; ++j) {
        float2 q = bucket[j];
        float l = bf2f(Lsb[(size_t)__float_as_int(q.x)*64 + lane]);
        acc += fmaxf(fmaf(q.y, w, rl + l), 0.f);
    }
    RlA[(size_t)node*64 + lane] = acc;
}

// =============== fused cons update ===============
// u = relu(agg@Fc + c0@OW0B + deg*gc + ob0);  Ls_c = u@Hc + hc  (bf16)
__global__ __launch_bounds__(256) void consupd_kernel(
    const float* __restrict__ aggpre, const u16* __restrict__ c0,
    const int* __restrict__ off,
    const float* __restrict__ Fc, const float* __restrict__ OW0B,
    const float* __restrict__ gc, const float* __restrict__ ob0,
    const float* __restrict__ Hc, const float* __restrict__ hc,
    u16* __restrict__ LsOut, int M)
{
    const int lane = threadIdx.x & 63;
    const int wv   = threadIdx.x >> 6;
    __shared__ __align__(16) float xs[4][8][64];
    __shared__ __align__(16) float cs[4][8][64];
    const int rowTile = (blockIdx.x*4 + wv)*8;

    float degv[8];
#pragma unroll
    for (int r = 0; r < 8; ++r) {
        int row = rowTile + r;
        int grow = (row < M) ? row : (M - 1);
        xs[wv][r][lane] = aggpre[(size_t)grow*64 + lane];
        cs[wv][r][lane] = bf2f(c0[(size_t)grow*64 + lane]);
        degv[r] = (float)(off[grow + 1] - off[grow]);
    }
    {
        float wa[64], wb[64];
#pragma unroll
        for (int k = 0; k < 64; ++k) { wa[k] = Fc[k*64 + lane]; wb[k] = OW0B[k*64 + lane]; }
        const float g_l = gc[lane], b_l = ob0[lane];
#pragma unroll
        for (int r = 0; r < 8; ++r) {
            float acc = fmaf(degv[r], g_l, b_l);
#pragma unroll
            for (int k4 = 0; k4 < 16; ++k4) {
                float4 x4 = *(const float4*)&xs[wv][r][k4*4];
                float4 c4 = *(const float4*)&cs[wv][r][k4*4];
                acc = fmaf(x4.x, wa[k4*4+0], acc); acc = fmaf(c4.x, wb[k4*4+0], acc);
                acc = fmaf(x4.y, wa[k4*4+1], acc); acc = fmaf(c4.y, wb[k4*4+1], acc);
                acc = fmaf(x4.z, wa[k4*4+2], acc); acc = fmaf(c4.z, wb[k4*4+2], acc);
                acc = fmaf(x4.w, wa[k4*4+3], acc); acc = fmaf(c4.w, wb[k4*4+3], acc);
            }
            xs[wv][r][lane] = fmaxf(acc, 0.f);
        }
    }
    {
        float wh[64];
#pragma unroll
        for (int k = 0; k < 64; ++k) wh[k] = Hc[k*64 + lane];
        const float h_l = hc[lane];
#pragma unroll
        for (int r = 0; r < 8; ++r) {
            float acc = h_l;
#pragma unroll
            for (int k4 = 0; k4 < 16; ++k4) {
                float4 u4 = *(const float4*)&xs[wv][r][k4*4];
                acc = fmaf(u4.x, wh[k4*4+0], acc);
                acc = fmaf(u4.y, wh[k4*4+1], acc);
                acc = fmaf(u4.z, wh[k4*4+2], acc);
                acc = fmaf(u4.w, wh[k4*4+3], acc);
            }
            int row = rowTile + r;
            if (row < M) LsOut[(size_t)row*64 + lane] = f2bf(acc);
        }
    }
}

// =============== fused var update + heads ===============
__global__ __launch_bounds__(256) void varupdhead_kernel(
    const float* __restrict__ aggpre, const u16* __restrict__ v0,
    const int* __restrict__ off,
    const float* __restrict__ Fv, const float* __restrict__ OW0B,
    const float* __restrict__ gv, const float* __restrict__ ob0,
    const float* __restrict__ Pw, const float* __restrict__ pbp, const float* __restrict__ pw1,
    const float* __restrict__ Vw, const float* __restrict__ vbp, const float* __restrict__ vw1,
    const float* __restrict__ vb1,
    float* __restrict__ out, int M)
{
    const int lane = threadIdx.x & 63;
    const int wv   = threadIdx.x >> 6;
    __shared__ __align__(16) float xs[4][8][64];
    __shared__ __align__(16) float cs[4][8][64];
    const int rowTile = (blockIdx.x*4 + wv)*8;

    float degv[8];
#pragma unroll
    for (int r = 0; r < 8; ++r) {
        int row = rowTile + r;
        int grow = (row < M) ? row : (M - 1);
        xs[wv][r][lane] = aggpre[(size_t)grow*64 + lane];
        cs[wv][r][lane] = bf2f(v0[(size_t)grow*64 + lane]);
        degv[r] = (float)(off[grow + 1] - off[grow]);
    }
    {
        float wa[64], wb[64];
#pragma unroll
        for (int k = 0; k < 64; ++k) { wa[k] = Fv[k*64 + lane]; wb[k] = OW0B[k*64 + lane]; }
        const float g_l = gv[lane], b_l = ob0[lane];
#pragma unroll
        for (int r = 0; r < 8; ++r) {
            float acc = fmaf(degv[r], g_l, b_l);
#pragma unroll
            for (int k4 = 0; k4 < 16; ++k4) {
                float4 x4 = *(const float4*)&xs[wv][r][k4*4];
                float4 c4 = *(const float4*)&cs[wv][r][k4*4];
                acc = fmaf(x4.x, wa[k4*4+0], acc); acc = fmaf(c4.x, wb[k4*4+0], acc);
                acc = fmaf(x4.y, wa[k4*4+1], acc); acc = fmaf(c4.y, wb[k4*4+1], acc);
                acc = fmaf(x4.z, wa[k4*4+2], acc); acc = fmaf(c4.z, wb[k4*4+2], acc);
                acc = fmaf(x4.w, wa[k4*4+3], acc); acc = fmaf(c4.w, wb[k4*4+3], acc);
            }
            xs[wv][r][lane] = fmaxf(acc, 0.f);
        }
    }
    {
        float wp[64], wq[64];
#pragma unroll
        for (int k = 0; k < 64; ++k) { wp[k] = Pw[k*64 + lane]; wq[k] = Vw[k*64 + lane]; }
        const float pb_l = pbp[lane], vb_l = vbp[lane];
        const float p1w = pw1[lane], v1w = vw1[lane];
        const float vbias = vb1[0];
#pragma unroll
        for (int r = 0; r < 8; ++r) {
            float tp = pb_l, tv = vb_l;
#pragma unroll
            for (int k4 = 0; k4 < 16; ++k4) {
                float4 u4 = *(const float4*)&xs[wv][r][k4*4];
                tp = fmaf(u4.x, wp[k4*4+0], tp); tv = fmaf(u4.x, wq[k4*4+0], tv);
                tp = fmaf(u4.y, wp[k4*4+1], tp); tv = fmaf(u4.y, wq[k4*4+1], tv);
                tp = fmaf(u4.z, wp[k4*4+2], tp); tv = fmaf(u4.z, wq[k4*4+2], tv);
                tp = fmaf(u4.w, wp[k4*4+3], tp); tv = fmaf(u4.w, wq[k4*4+3], tv);
            }
            tp = fmaxf(tp, 0.f) * p1w;
            tv = fmaxf(tv, 0.f) * v1w;
#pragma unroll
            for (int m = 32; m >= 1; m >>= 1) {
                tp += __shfl_xor(tp, m, 64);
                tv += __shfl_xor(tv, m, 64);
            }
            int row = rowTile + r;
            if (lane == 0 && row < M) {
                out[row]     = tv + vbias;  // value
                out[M + row] = tp;          // policy
            }
        }
    }
}

// =============== host launch ===============
#define AL256(x) (((x) + 255) & ~(size_t)255)

extern "C" void kernel_launch(void* const* d_in, const int* in_sizes, int n_in,
                              void* d_out, int out_size, void* d_ws, size_t ws_size,
                              hipStream_t stream)
{
    const float* cf  = (const float*)d_in[0];
    const int*   ei  = (const int*)  d_in[1];
    const float* ef  = (const float*)d_in[2];
    const float* vf  = (const float*)d_in[3];

    const float* cw0 = (const float*)d_in[4];
    const float* cb0 = (const float*)d_in[5];
    const float* cw1 = (const float*)d_in[6];
    const float* cb1 = (const float*)d_in[7];
    const float* vw0 = (const float*)d_in[8];
    const float* vb0 = (const float*)d_in[9];
    const float* vw1 = (const float*)d_in[10];
    const float* vb1 = (const float*)d_in[11];

    const float* vc_lw  = (const float*)d_in[12];
    const float* vc_lb  = (const float*)d_in[13];
    const float* vc_ew  = (const float*)d_in[14];
    const float* vc_rw  = (const float*)d_in[15];
    const float* vc_fw  = (const float*)d_in[16];
    const float* vc_fb  = (const float*)d_in[17];
    const float* vc_ow0 = (const float*)d_in[18];
    const float* vc_ob0 = (const float*)d_in[19];
    const float* vc_ow1 = (const float*)d_in[20];
    const float* vc_ob1 = (const float*)d_in[21];

    const float* cv_lw  = (const float*)d_in[22];
    const float* cv_lb  = (const float*)d_in[23];
    const float* cv_ew  = (const float*)d_in[24];
    const float* cv_rw  = (const float*)d_in[25];
    const float* cv_fw  = (const float*)d_in[26];
    const float* cv_fb  = (const float*)d_in[27];
    const float* cv_ow0 = (const float*)d_in[28];
    const float* cv_ob0 = (const float*)d_in[29];
    const float* cv_ow1 = (const float*)d_in[30];
    const float* cv_ob1 = (const float*)d_in[31];

    const float* pw0  = (const float*)d_in[32];
    const float* pb0  = (const float*)d_in[33];
    const float* pw1  = (const float*)d_in[34];
    const float* vhw0 = (const float*)d_in[35];
    const float* vhb0 = (const float*)d_in[36];
    const float* vhw1 = (const float*)d_in[37];
    const float* vhb1 = (const float*)d_in[38];

    const int NC = in_sizes[0] / 5;
    const int E  = in_sizes[1] / 2;
    const int NV = in_sizes[3] / 19;
    const int* eic = ei;
    const int* eiv = ei + E;

    // ---- workspace layout (explicit byte offsets, 256B aligned) ----
    char* base = (char*)d_ws;
    size_t o = 0;
    float*  RlC = (float*)(base + o);  o += AL256((size_t)NC*64*4);
    u16*    c0b = (u16*)  (base + o);  o += AL256((size_t)NC*64*2);
    u16*    LsC = (u16*)  (base + o);  o += AL256((size_t)NC*64*2);
    float*  RlV = (float*)(base + o);  o += AL256((size_t)NV*64*4);
    u16*    v0b = (u16*)  (base + o);  o += AL256((size_t)NV*64*2);
    u16*    LsV = (u16*)  (base + o);  o += AL256((size_t)NV*64*2);
    float2* bkt = (float2*)(base + o); o += AL256((size_t)E*8);
    int* cntC = (int*)(base + o);  o += AL256((size_t)NC*4);
    int* offC = (int*)(base + o);  o += AL256(((size_t)NC + 1)*4);
    int* cntV = (int*)(base + o);  o += AL256((size_t)NV*4);
    int* offV = (int*)(base + o);  o += AL256(((size_t)NV + 1)*4);
    int* blks = (int*)(base + o);  o += AL256((size_t)1024*4);
    int* blkex= (int*)(base + o);  o += AL256((size_t)1024*4);
    float* Fc  = (float*)(base + o); o += AL256((size_t)4096*4);
    float* Hc  = (float*)(base + o); o += AL256((size_t)4096*4);
    float* Fv  = (float*)(base + o); o += AL256((size_t)4096*4);
    float* Pw  = (float*)(base + o); o += AL256((size_t)4096*4);
    float* Vw  = (float*)(base + o); o += AL256((size_t)4096*4);
    float* gc  = (float*)(base + o); o += AL256((size_t)64*4);
    float* hc  = (float*)(base + o); o += AL256((size_t)64*4);
    float* gv  = (float*)(base + o); o += AL256((size_t)64*4);
    float* pbp = (float*)(base + o); o += AL256((size_t)64*4);
    float* vbp = (float*)(base + o); o += AL256((size_t)64*4);

    if (o > ws_size) return;  // insufficient scratch: fail visibly

    dim3 blk(256);
    dim3 gRowsC((unsigned)((NC + 31) / 32));
    dim3 gRowsV((unsigned)((NV + 31) / 32));
    dim3 gNodeC((unsigned)((NC + 3) / 4));
    dim3 gNodeV((unsigned)((NV + 3) / 4));
    dim3 gE((unsigned)((E + 255) / 256));
    const int nbC = (NC + 1023) / 1024;
    const int nbV = (NV + 1023) / 1024;

    // ---- counting sort setup ----
    (void)hipMemsetAsync(cntC, 0, (size_t)NC*4, stream);
    (void)hipMemsetAsync(cntV, 0, (size_t)NV*4, stream);
    hist2_kernel<<<gE, blk, 0, stream>>>(eic, eiv, cntC, cntV, E);
    scan1_kernel<<<dim3(nbC), blk, 0, stream>>>(cntC, blks, NC);
    scan2_kernel<<<dim3(1),   blk, 0, stream>>>(blks, blkex, nbC);
    scan3_kernel<<<dim3(nbC), blk, 0, stream>>>(cntC, blkex, offC, NC);
    scan1_kernel<<<dim3(nbV), blk, 0, stream>>>(cntV, blks, NV);
    scan2_kernel<<<dim3(1),   blk, 0, stream>>>(blks, blkex, nbV);
    scan3_kernel<<<dim3(nbV), blk, 0, stream>>>(cntV, blkex, offV, NV);

    // ---- collapsed weights ----
    prep_kernel<<<dim3(1), blk, 0, stream>>>(
        vc_fw, vc_fb, vc_ow0, vc_ow1, vc_ob1,
        cv_rw, cv_fw, cv_fb, cv_ow0, cv_ow1, cv_ob1,
        pw0, pb0, vhw0, vhb0,
        Fc, gc, Hc, hc, Fv, gv, Pw, pbp, Vw, vbp);

    // ---- embeddings (+ fused per-node linears) ----
    embc_kernel<<<gRowsC, blk, 0, stream>>>(cf, cw0, cb0, cw1, cb1,
                                            vc_lw, vc_lb, c0b, RlC, NC);
    embv_kernel<<<gRowsV, blk, 0, stream>>>(vf, vw0, vb0, vw1, vb1,
                                            vc_rw, cv_lw, cv_lb, v0b, LsV, RlV, NV);

    // ---- conv1: v -> c ----
    (void)hipMemcpyAsync(cntC, offC, (size_t)NC*4, hipMemcpyDeviceToDevice, stream);
    scatter1_kernel<<<gE, blk, 0, stream>>>(eic, eiv, ef, cntC, bkt, E);
    agg_kernel<<<gNodeC, blk, 0, stream>>>(offC, bkt, RlC, LsV, vc_ew, NC);
    consupd_kernel<<<gRowsC, blk, 0, stream>>>(RlC, c0b, offC,
                                               Fc, vc_ow0 + 64*64, gc, vc_ob0,
                                               Hc, hc, LsC, NC);

    // ---- conv2: c -> v ----
    (void)hipMemcpyAsync(cntV, offV, (size_t)NV*4, hipMemcpyDeviceToDevice, stream);
    scatter1_kernel<<<gE, blk, 0, stream>>>(eiv, eic, ef, cntV, bkt, E);
    agg_kernel<<<gNodeV, blk, 0, stream>>>(offV, bkt, RlV, LsC, cv_ew, NV);
    varupdhead_kernel<<<gRowsV, blk, 0, stream>>>(RlV, v0b, offV,
                                                  Fv, cv_ow0 + 64*64, gv, cv_ob0,
                                                  Pw, pbp, pw1, Vw, vbp, vhw1, vhb1,
                                                  (float*)d_out, NV);
}